// Round 1
// baseline (181.332 us; speedup 1.0000x reference)
//
#include <hip/hip_runtime.h>
#include <cstddef>

#define CC 128
#define NH 8
#define HD 16
#define DDIM 31
#define HWW 1024
#define TOK 31744   // DDIM * HWW
#define SCALE2 0.0625f   // (HD^-0.5)^2 — both QK^T operands pre-scaled in the ref
#define QTOK 64     // qproj token tile (r15: 64 -> grid 496 -> 2 blocks/CU)

typedef __attribute__((ext_vector_type(4))) short  short4v;
typedef __attribute__((ext_vector_type(4))) float  float4v;
typedef __attribute__((ext_vector_type(2))) unsigned uint2v;

__device__ inline unsigned bf16rne(float f) {
    unsigned u = __float_as_uint(f);
    return (u + 0x7fffu + ((u >> 16) & 1u)) >> 16;
}
__device__ inline float bf2f(unsigned h) { return __uint_as_float(h << 16); }

// Packed activation element: dword = hi_bf16 | (lo_bf16 << 16).
__device__ inline unsigned packsplit(float v) {
    unsigned h = bf16rne(v);
    unsigned l = bf16rne(v - bf2f(h));
    return h | (l << 16);
}
__device__ inline uint2 pack_hi4(uint4 p) {
    return make_uint2((p.x & 0xffffu) | (p.y << 16),
                      (p.z & 0xffffu) | (p.w << 16));
}
__device__ inline uint2 pack_lo4(uint4 p) {
    return make_uint2((p.x >> 16) | (p.y & 0xffff0000u),
                      (p.z >> 16) | (p.w & 0xffff0000u));
}

// r15: bf16-truncate pack of 4 exp'd scores via 2x v_perm_b32 (bit-identical
// to the old 4x (short)(u>>16) path, ~4 fewer VALU ops per score tile).
__device__ inline short4v pack_pf(unsigned u0, unsigned u1,
                                  unsigned u2, unsigned u3) {
    uint2v pd;
    pd[0] = __builtin_amdgcn_perm(u1, u0, 0x07060302u);  // [u0.hi16 | u1.hi16<<16]
    pd[1] = __builtin_amdgcn_perm(u3, u2, 0x07060302u);
    return __builtin_bit_cast(short4v, pd);
}

// Load a wave's W^T A-frags (16 co x 128 k) from global W[k][co], split to
// bf16 hi/lo in-register. Weights are L2/L3-hot across blocks.
__device__ inline void load_wfrags(const float* __restrict__ W, int co0, int l,
                                   int quad, short4v* ah, short4v* al)
{
#pragma unroll
    for (int k8 = 0; k8 < 8; ++k8) {
#pragma unroll
        for (int j = 0; j < 4; ++j) {
            float w = W[(size_t)(k8 * 16 + quad * 4 + j) * CC + co0 + l];
            unsigned h = bf16rne(w);
            ah[k8][j] = (short)h;
            al[k8][j] = (short)bf16rne(w - bf2f(h));
        }
    }
}

#define AST 132   // LDS act row stride (ushorts)

// ---------------------------------------------------------------------------
// Kernel 1: Q projection, BOTH branches per block (x staged once).
// r15: 64-token tiles, grid 496, __launch_bounds__(512,4) (128-VGPR cap,
// acc[2][4]+frags ~120 regs fits) -> 2 blocks/CU = 16 waves/CU, up from
// 1 block/CU (grid 248 could never place a 2nd block on 256 CUs).
// ---------------------------------------------------------------------------
__global__ __launch_bounds__(512, 4) void qproj_kernel(
    const float* __restrict__ x,
    const float* __restrict__ Wq1, const float* __restrict__ Wq2,
    const float* __restrict__ bq1, const float* __restrict__ bq2,
    unsigned* __restrict__ q1p, unsigned* __restrict__ q2p,
    float* __restrict__ sums)
{
    __shared__ ushort sbuf[2 * QTOK * AST];   // 33.8 KB: x hi/lo, then out staging
    ushort* Ahi = sbuf;
    ushort* Alo = sbuf + QTOK * AST;
    unsigned* S = (unsigned*)sbuf;            // 64 x 132 dwords (exact fit)
    const int tid = threadIdx.x;
    const int t0  = blockIdx.x * QTOK;
    if (blockIdx.x == 0 && tid < 2 * CC) sums[tid] = 0.f;   // for attn's atomics

    // stage x tile transposed + split: [t][ci] (once, shared by both branches)
    for (int i = tid; i < CC * QTOK / 4; i += 512) {
        int t4 = i & 15, ci = i >> 4;
        float4 v = *(const float4*)&x[(size_t)ci * TOK + t0 + t4 * 4];
        float xv[4] = {v.x, v.y, v.z, v.w};
#pragma unroll
        for (int e = 0; e < 4; ++e) {
            unsigned h = bf16rne(xv[e]);
            unsigned lw = bf16rne(xv[e] - bf2f(h));
            Ahi[(t4 * 4 + e) * AST + ci] = (ushort)h;
            Alo[(t4 * 4 + e) * AST + ci] = (ushort)lw;
        }
    }
    __syncthreads();

    const int lane = tid & 63;
    const int l    = lane & 15;
    const int quad = lane >> 4;
    const int co0  = (tid >> 6) * 16;

    // weight frags for BOTH branches live; one shared pass over LDS B-frags
    short4v ah[2][8], al[2][8];
    load_wfrags(Wq1, co0, l, quad, ah[0], al[0]);
    load_wfrags(Wq2, co0, l, quad, ah[1], al[1]);
    float4v acc[2][4];
#pragma unroll
    for (int br = 0; br < 2; ++br)
#pragma unroll
        for (int nt = 0; nt < 4; ++nt) acc[br][nt] = (float4v){0.f, 0.f, 0.f, 0.f};
#pragma unroll
    for (int k8 = 0; k8 < 8; ++k8) {
#pragma unroll
        for (int nt = 0; nt < 4; ++nt) {
            short4v bh = *(const short4v*)&Ahi[(nt * 16 + l) * AST + k8 * 16 + quad * 4];
            short4v bl = *(const short4v*)&Alo[(nt * 16 + l) * AST + k8 * 16 + quad * 4];
            acc[0][nt] = __builtin_amdgcn_mfma_f32_16x16x16bf16_1k(ah[0][k8], bh, acc[0][nt], 0, 0, 0);
            acc[0][nt] = __builtin_amdgcn_mfma_f32_16x16x16bf16_1k(ah[0][k8], bl, acc[0][nt], 0, 0, 0);
            acc[0][nt] = __builtin_amdgcn_mfma_f32_16x16x16bf16_1k(al[0][k8], bh, acc[0][nt], 0, 0, 0);
            acc[1][nt] = __builtin_amdgcn_mfma_f32_16x16x16bf16_1k(ah[1][k8], bh, acc[1][nt], 0, 0, 0);
            acc[1][nt] = __builtin_amdgcn_mfma_f32_16x16x16bf16_1k(ah[1][k8], bl, acc[1][nt], 0, 0, 0);
            acc[1][nt] = __builtin_amdgcn_mfma_f32_16x16x16bf16_1k(al[1][k8], bh, acc[1][nt], 0, 0, 0);
        }
    }

    // staged epilogues: LDS tile then contiguous full-line stores
    for (int branch = 0; branch < 2; ++branch) {
        const float* bq = branch ? bq2 : bq1;
        unsigned* op    = branch ? q2p : q1p;
        float4 bv = *(const float4*)&bq[co0 + quad * 4];
        float bb[4] = {bv.x, bv.y, bv.z, bv.w};
        __syncthreads();   // previous use of sbuf done
#pragma unroll
        for (int nt = 0; nt < 4; ++nt) {
#pragma unroll
            for (int reg = 0; reg < 4; ++reg)
                S[(nt * 16 + l) * AST + co0 + quad * 4 + reg] =
                    packsplit(acc[branch][nt][reg] + bb[reg]);
        }
        __syncthreads();
        for (int i = tid; i < QTOK * 32; i += 512) {
            int t = i >> 5, c4 = i & 31;
            uint4 pv = *(const uint4*)&S[t * AST + c4 * 4];
            *(uint4*)&op[(size_t)(t0 + t) * CC + c4 * 4] = pv;   // 512 B/32 lanes
        }
    }
}

// ---------------------------------------------------------------------------
// Kernel 2: FUSED attention.
// r15 SPLIT=1: grid 496, TWO blocks per (d,h) each owning 512 queries.
// LDS 75.3 KB x2 fits 160 KB -> 2 blocks/CU = 32 waves/CU (was capped at 1
// block/CU by the 248-block grid; counters showed Occ 34%, both pipes <50%).
// Write hazard (sibling block stages keys from q2p while we write) is removed
// by writing spatial O to a SEPARATE plane q2out; oproj reads it from there.
// SPLIT=0 is the old in-place single-block path (ws too small fallback).
// Phase 2 spectral: identical body, jobs spread over every 4th block.
// ---------------------------------------------------------------------------
#define QS2 132
#define QSS 20
#define QTP 1044
template<int SPLIT>
__global__ __launch_bounds__(1024, SPLIT ? 8 : 4) void attn_kernel(
    unsigned* __restrict__ q1p, const unsigned* q2p,
    unsigned* q2out, float* __restrict__ sums)
{
    constexpr int NLT = SPLIT ? 2 : 4;
    __shared__ __align__(16) ushort smem[HWW * QSS + HD * QTP];  // 74.4 KB
    __shared__ float fsum[CC];
    const int tid  = threadIdx.x;
    const int lane = tid & 63;
    const int l    = lane & 15;
    const int quad = lane >> 4;
    const float k2 = SCALE2 * 1.44269504f;
    const short4v onesb = {(short)0x3F80, (short)0x3F80, (short)0x3F80, (short)0x3F80};
    if (tid < CC) fsum[tid] = 0.f;

    // ---------------- phase 1: spatial slice (O^T form) ----------------
    {
        const int sp    = SPLIT ? (int)(blockIdx.x >> 1) : (int)blockIdx.x;
        const int qhalf = SPLIT ? (int)(blockIdx.x & 1) : 0;
        const int d = sp >> 3, h = sp & 7;
        ushort* Qs  = smem;
        ushort* QTs = smem + HWW * QSS;
        const size_t base = (size_t)d * HWW * CC + h * HD;   // dword index

        for (int i = tid; i < HWW * 4; i += 1024) {
            int row = i >> 2, q4 = i & 3;
            uint4 p = *(const uint4*)&q2p[base + (size_t)row * CC + q4 * 4];
            *(uint2*)&Qs[row * QSS + q4 * 4] = pack_hi4(p);
            QTs[(q4 * 4 + 0) * QTP + row] = (ushort)p.x;
            QTs[(q4 * 4 + 1) * QTP + row] = (ushort)p.y;
            QTs[(q4 * 4 + 2) * QTP + row] = (ushort)p.z;
            QTs[(q4 * 4 + 3) * QTP + row] = (ushort)p.w;
        }
        __syncthreads();

        const int Rw = qhalf * 512 + (tid >> 6) * (NLT * 16);
        short4v qf[NLT];
#pragma unroll
        for (int lt = 0; lt < NLT; ++lt) {
            short4v raw = *(short4v*)&Qs[(Rw + lt * 16 + l) * QSS + quad * 4];
            short4v sc;
#pragma unroll
            for (int e = 0; e < 4; ++e) {
                float f = bf2f((unsigned)(ushort)raw[e]) * k2;
                sc[e] = (short)bf16rne(f);
            }
            qf[lt] = sc;
        }

        float4v acc[NLT], accs[NLT];
#pragma unroll
        for (int lt = 0; lt < NLT; ++lt) {
            acc[lt]  = (float4v){0.f, 0.f, 0.f, 0.f};
            accs[lt] = (float4v){0.f, 0.f, 0.f, 0.f};
        }

#pragma unroll 2
        for (int mt = 0; mt < 64; ++mt) {
            const int m0 = mt * 16;
            short4v ka = *(short4v*)&Qs[(m0 + l) * QSS + quad * 4];
            short4v vb = *(short4v*)&QTs[l * QTP + m0 + quad * 4];   // V^T A-frag
#pragma unroll
            for (int lt = 0; lt < NLT; ++lt) {
                float4v s = __builtin_amdgcn_mfma_f32_16x16x16bf16_1k(
                    ka, qf[lt], (float4v){0.f, 0.f, 0.f, 0.f}, 0, 0, 0);
                unsigned u0 = __float_as_uint(__builtin_amdgcn_exp2f(s[0]));
                unsigned u1 = __float_as_uint(__builtin_amdgcn_exp2f(s[1]));
                unsigned u2 = __float_as_uint(__builtin_amdgcn_exp2f(s[2]));
                unsigned u3 = __float_as_uint(__builtin_amdgcn_exp2f(s[3]));
                short4v pf = pack_pf(u0, u1, u2, u3);
                // O^T[channel][query] += V^T · P^T ; denom via A=ones
                acc[lt]  = __builtin_amdgcn_mfma_f32_16x16x16bf16_1k(vb, pf, acc[lt], 0, 0, 0);
                accs[lt] = __builtin_amdgcn_mfma_f32_16x16x16bf16_1k(onesb, pf, accs[lt], 0, 0, 0);
            }
        }

        float vsum[4] = {0.f, 0.f, 0.f, 0.f};
#pragma unroll
        for (int lt = 0; lt < NLT; ++lt) {
            float inv = 1.f / accs[lt][0];   // denom(query = Rw+lt*16+l); rows equal
            int token = Rw + lt * 16 + l;
            float v0 = acc[lt][0] * inv, v1 = acc[lt][1] * inv;
            float v2 = acc[lt][2] * inv, v3 = acc[lt][3] * inv;
            uint4 pv;
            pv.x = packsplit(v0); pv.y = packsplit(v1);
            pv.z = packsplit(v2); pv.w = packsplit(v3);
            *(uint4*)&q2out[base + (size_t)token * CC + quad * 4] = pv;
            vsum[0] += v0; vsum[1] += v1; vsum[2] += v2; vsum[3] += v3;
        }
#pragma unroll
        for (int reg = 0; reg < 4; ++reg) {
            float v = vsum[reg];
            v += __shfl_xor(v, 1); v += __shfl_xor(v, 2);
            v += __shfl_xor(v, 4); v += __shfl_xor(v, 8);
            if (l == 0) atomicAdd(&fsum[quad * 4 + reg], v);
        }
        __syncthreads();
        if (tid < HD) atomicAdd(&sums[CC + h * HD + tid], fsum[tid]);
    }

    // ---------------- phase 2: spectral job (if assigned) ----------------
    int job;
    bool has_job;
    if (SPLIT) {
        const int m4  = blockIdx.x & 3;
        const int q4b = blockIdx.x >> 2;
        has_job = (m4 == 0) ? (q4b < 124) : ((m4 == 2) && (q4b < 4));
        job = (m4 == 0) ? q4b : (124 + q4b);
    } else {
        const int half_id = blockIdx.x >> 1;
        has_job = (blockIdx.x & 1) ? (half_id < 4) : (half_id < 124);
        job = (blockIdx.x & 1) ? (124 + half_id) : half_id;
    }
    if (!has_job) return;
    const int hw0 = job * 8;

    __syncthreads();                       // phase-1 smem reads + fsum use done
    if (tid < CC) fsum[tid] = 0.f;

    const int wave = tid >> 6;
    const int hwl  = wave >> 1;
    const int half = wave & 1;
    const int hw   = hw0 + hwl;
    ushort* Q = smem + hwl * (32 * QS2);
    for (int it = 0; it < 8; ++it) {
        int idx = it * 64 + lane;
        int dd = half * 16 + (idx >> 5), c4 = idx & 31;
        if (dd < 31) {
            uint4 p = *(const uint4*)&q1p[((size_t)dd * HWW + hw) * CC + c4 * 4];
            *(uint2*)&Q[dd * QS2 + c4 * 4] = pack_hi4(p);
        }
    }
    if (half) for (int i = lane; i < 128; i += 64) Q[31 * QS2 + i] = 0;
    __syncthreads();

    const int hh = half * 4;
#pragma unroll
    for (int hl = 0; hl < 4; ++hl) {
        const int hc = (hh + hl) * HD;
        short4v qf[2];
        qf[0] = *(const short4v*)&Q[l * QS2 + hc + quad * 4];
        qf[1] = *(const short4v*)&Q[(16 + l) * QS2 + hc + quad * 4];
        short4v va[2];
#pragma unroll
        for (int j = 0; j < 2; ++j)
#pragma unroll
            for (int jj = 0; jj < 4; ++jj)
                va[j][jj] = (short)Q[(j * 16 + quad * 4 + jj) * QS2 + hc + l];

        float4v o[2]   = {(float4v){0.f,0.f,0.f,0.f}, (float4v){0.f,0.f,0.f,0.f}};
        float4v osr[2] = {(float4v){0.f,0.f,0.f,0.f}, (float4v){0.f,0.f,0.f,0.f}};
#pragma unroll
        for (int j = 0; j < 2; ++j) {
#pragma unroll
            for (int i2 = 0; i2 < 2; ++i2) {
                float4v s = __builtin_amdgcn_mfma_f32_16x16x16bf16_1k(
                    qf[j], qf[i2], (float4v){0.f,0.f,0.f,0.f}, 0, 0, 0);
                unsigned u0 = __float_as_uint(__builtin_amdgcn_exp2f(s[0] * k2));
                unsigned u1 = __float_as_uint(__builtin_amdgcn_exp2f(s[1] * k2));
                unsigned u2 = __float_as_uint(__builtin_amdgcn_exp2f(s[2] * k2));
                unsigned u3 = __float_as_uint(__builtin_amdgcn_exp2f(s[3] * k2));
                if (j == 1 && quad == 3) u3 = 0;   // mask key 31
                short4v pf = pack_pf(u0, u1, u2, u3);
                o[i2]   = __builtin_amdgcn_mfma_f32_16x16x16bf16_1k(va[j], pf, o[i2], 0, 0, 0);
                osr[i2] = __builtin_amdgcn_mfma_f32_16x16x16bf16_1k(onesb, pf, osr[i2], 0, 0, 0);
            }
        }
        float vsum[4] = {0.f, 0.f, 0.f, 0.f};
#pragma unroll
        for (int i2 = 0; i2 < 2; ++i2) {
            float inv = 1.f / osr[i2][0];   // rowsum(query=i2*16+l), this lane
            int dq = i2 * 16 + l;
            if (dq < 31) {
                uint4 pv;
                float v0 = o[i2][0] * inv, v1 = o[i2][1] * inv;
                float v2 = o[i2][2] * inv, v3 = o[i2][3] * inv;
                pv.x = packsplit(v0); pv.y = packsplit(v1);
                pv.z = packsplit(v2); pv.w = packsplit(v3);
                *(uint4*)&q1p[((size_t)dq * HWW + hw) * CC + hc + quad * 4] = pv;
                vsum[0] += v0; vsum[1] += v1; vsum[2] += v2; vsum[3] += v3;
            }
        }
#pragma unroll
        for (int r = 0; r < 4; ++r) {
            float v = vsum[r];
            v += __shfl_xor(v, 1); v += __shfl_xor(v, 2);
            v += __shfl_xor(v, 4); v += __shfl_xor(v, 8);
            if (l == 0) atomicAdd(&fsum[hc + quad * 4 + r], v);
        }
    }
    __syncthreads();
    if (tid < CC) atomicAdd(&sums[tid], fsum[tid]);
}

// ---------------------------------------------------------------------------
// Kernel 3: output projection + in-block gate, BOTH branches, 64-token tiles.
// r15: __launch_bounds__(512,4) caps VGPR at 128 (est. peak ~85) so the
// 33.8+3.5 KB LDS footprint actually yields 2 blocks/CU.
// Spatial branch now read from q2pb (attn's separate output plane).
// ---------------------------------------------------------------------------
__global__ __launch_bounds__(512, 4) void oproj_kernel(
    const unsigned* __restrict__ q1p, const unsigned* __restrict__ q2p,
    const float* __restrict__ Wp1, const float* __restrict__ Wp2,
    const float* __restrict__ bp1, const float* __restrict__ bp2,
    const float* __restrict__ Wg,  const float* __restrict__ bg,
    const float* __restrict__ sums, float* __restrict__ out)
{
    __shared__ ushort sbuf[2 * 64 * AST];   // 33.8 KB: act hi/lo, then out staging
    ushort* Ahi = sbuf;
    ushort* Alo = sbuf + 64 * AST;
    unsigned* S = (unsigned*)sbuf;          // 128 x 66 dwords (exact fit)
    __shared__ float pa[4][CC];
    __shared__ float giv[2 * CC];
    __shared__ float gf[CC];
    const int tid = threadIdx.x;
    const int t0  = blockIdx.x * 64;
    const int lane = tid & 63;
    const int l    = lane & 15;
    const int quad = lane >> 4;
    const int co0  = (tid >> 6) * 16;

    // ---- gate phase (two-stage GEMV from sums; exact reference math) ----
    {
        const int part = tid >> 7, c = tid & 127;
        const float* Wp = (part < 2) ? Wp1 : Wp2;
        const float* sp = (part < 2) ? sums : sums + CC;
        const int k0 = (part & 1) * 64;
        float a = 0.f;
        for (int kk = 0; kk < 64; ++kk) {
            int k = k0 + kk;
            a += sp[k] * Wp[(size_t)k * CC + c];
        }
        pa[part][c] = a;
        __syncthreads();
        if (tid < 2 * CC) {
            float m = (tid < CC) ? (pa[0][tid] + pa[1][tid])
                                 : (pa[2][tid - CC] + pa[3][tid - CC]);
            float bb = (tid < CC) ? bp1[tid] : bp2[tid - CC];
            giv[tid] = m * (1.f / (float)TOK) + bb;
        }
        __syncthreads();
        float b = 0.f;
        for (int kk = 0; kk < 64; ++kk) {
            int j = part * 64 + kk;
            b += giv[j] * Wg[(size_t)j * CC + c];
        }
        pa[part][c] = b;
        __syncthreads();
        if (tid < CC)
            gf[tid] = 1.f / (1.f + __expf(-(bg[tid] + pa[0][tid] + pa[1][tid] +
                                           pa[2][tid] + pa[3][tid])));
    }

    // ---- main GEMM ----
    float4v acc[2][4];
#pragma unroll
    for (int br = 0; br < 2; ++br)
#pragma unroll
        for (int nt = 0; nt < 4; ++nt) acc[br][nt] = (float4v){0.f, 0.f, 0.f, 0.f};

    for (int br = 0; br < 2; ++br) {
        const unsigned* Ap = br ? q2p : q1p;
        const float*    W  = br ? Wp2 : Wp1;
        short4v ah[8], al[8];
        load_wfrags(W, co0, l, quad, ah, al);
        __syncthreads();   // previous phase/branch LDS reads done
        for (int i = tid; i < 64 * 32; i += 512) {
            int t = i >> 5, c4 = i & 31;
            uint4 p = *(const uint4*)&Ap[(size_t)(t0 + t) * CC + c4 * 4];
            *(uint2*)&Ahi[t * AST + c4 * 4] = pack_hi4(p);
            *(uint2*)&Alo[t * AST + c4 * 4] = pack_lo4(p);
        }
        __syncthreads();
#pragma unroll
        for (int k8 = 0; k8 < 8; ++k8) {
#pragma unroll
            for (int nt = 0; nt < 4; ++nt) {
                short4v bh = *(const short4v*)&Ahi[(nt * 16 + l) * AST + k8 * 16 + quad * 4];
                short4v bl = *(const short4v*)&Alo[(nt * 16 + l) * AST + k8 * 16 + quad * 4];
                acc[br][nt] = __builtin_amdgcn_mfma_f32_16x16x16bf16_1k(ah[k8], bh, acc[br][nt], 0, 0, 0);
                acc[br][nt] = __builtin_amdgcn_mfma_f32_16x16x16bf16_1k(ah[k8], bl, acc[br][nt], 0, 0, 0);
                acc[br][nt] = __builtin_amdgcn_mfma_f32_16x16x16bf16_1k(al[k8], bh, acc[br][nt], 0, 0, 0);
            }
        }
    }

    float4 b1 = *(const float4*)&bp1[co0 + quad * 4];
    float4 b2 = *(const float4*)&bp2[co0 + quad * 4];
    float bb1[4] = {b1.x, b1.y, b1.z, b1.w};
    float bb2[4] = {b2.x, b2.y, b2.z, b2.w};
    float gg[4];
#pragma unroll
    for (int e = 0; e < 4; ++e) gg[e] = gf[co0 + quad * 4 + e];

    // staged epilogue: [co][t] tile in LDS (stride 66), then contiguous stores
    __syncthreads();   // act LDS reads done
#pragma unroll
    for (int nt = 0; nt < 4; ++nt) {
        int tl = nt * 16 + l;
#pragma unroll
        for (int reg = 0; reg < 4; ++reg) {
            float v = gg[reg] * (acc[0][nt][reg] + bb1[reg]) +
                      (1.f - gg[reg]) * (acc[1][nt][reg] + bb2[reg]);
            S[(co0 + quad * 4 + reg) * 66 + tl] = __float_as_uint(v);
        }
    }
    __syncthreads();
    for (int i = tid; i < 128 * 32; i += 512) {
        int co = i >> 5, t2 = i & 31;
        uint2 v = *(const uint2*)&S[co * 66 + t2 * 2];
        *(uint2*)&out[(size_t)co * TOK + t0 + t2 * 2] = v;   // 256 B/32 lanes
    }
}

extern "C" void kernel_launch(void* const* d_in, const int* in_sizes, int n_in,
                              void* d_out, int out_size, void* d_ws, size_t ws_size,
                              hipStream_t stream)
{
    const float* x   = (const float*)d_in[0];
    const float* Wq1 = (const float*)d_in[1];
    const float* bq1 = (const float*)d_in[2];
    const float* Wp1 = (const float*)d_in[3];
    const float* bp1 = (const float*)d_in[4];
    const float* Wq2 = (const float*)d_in[5];
    const float* bq2 = (const float*)d_in[6];
    const float* Wp2 = (const float*)d_in[7];
    const float* bp2 = (const float*)d_in[8];
    const float* Wg  = (const float*)d_in[9];
    const float* bg  = (const float*)d_in[10];
    float* out = (float*)d_out;

    const size_t plane = (size_t)TOK * CC;             // dwords per packed plane
    unsigned* q1p = (unsigned*)d_ws;
    unsigned* q2p = q1p + plane;
    // r15: split attn needs a 3rd plane (spatial O written out-of-place so two
    // blocks per (d,h) never race the sibling's key staging). Fall back to the
    // old in-place single-block path if the workspace is too small.
    const bool split = ws_size >= (3 * plane * sizeof(unsigned) + 1024 * sizeof(float));
    unsigned* q2pb = split ? (q2p + plane) : q2p;
    float*   sums  = (float*)(q2pb + plane);           // 256 floats (zeroed by qproj)

    qproj_kernel<<<dim3(TOK / QTOK), 512, 0, stream>>>(x, Wq1, Wq2, bq1, bq2,
                                                       q1p, q2p, sums);
    if (split)
        attn_kernel<1><<<dim3(496), 1024, 0, stream>>>(q1p, q2p, q2pb, sums);
    else
        attn_kernel<0><<<dim3(248), 1024, 0, stream>>>(q1p, q2p, q2p, sums);
    oproj_kernel<<<dim3(496), 512, 0, stream>>>(q1p, q2pb,
                                                Wp1, Wp2, bp1, bp2, Wg, bg,
                                                sums, out);
}

// Round 2
// 173.045 us; speedup vs baseline: 1.0479x; 1.0479x over previous
//
#include <hip/hip_runtime.h>
#include <cstddef>

#define CC 128
#define NH 8
#define HD 16
#define DDIM 31
#define HWW 1024
#define TOK 31744   // DDIM * HWW
#define SCALE2 0.0625f   // (HD^-0.5)^2 — both QK^T operands pre-scaled in the ref
#define QTOK 64     // qproj token tile (grid 496 -> 2 blocks/CU)

typedef __attribute__((ext_vector_type(4))) short  short4v;
typedef __attribute__((ext_vector_type(8))) short  short8v;
typedef __attribute__((ext_vector_type(4))) float  float4v;
typedef __attribute__((ext_vector_type(2))) unsigned uint2v;
typedef __attribute__((ext_vector_type(8))) __bf16 bf16x8;

__device__ inline unsigned bf16rne(float f) {
    unsigned u = __float_as_uint(f);
    return (u + 0x7fffu + ((u >> 16) & 1u)) >> 16;
}
__device__ inline float bf2f(unsigned h) { return __uint_as_float(h << 16); }

// Packed activation element: dword = hi_bf16 | (lo_bf16 << 16).
__device__ inline unsigned packsplit(float v) {
    unsigned h = bf16rne(v);
    unsigned l = bf16rne(v - bf2f(h));
    return h | (l << 16);
}
__device__ inline uint2 pack_hi4(uint4 p) {
    return make_uint2((p.x & 0xffffu) | (p.y << 16),
                      (p.z & 0xffffu) | (p.w << 16));
}
__device__ inline uint2 pack_lo4(uint4 p) {
    return make_uint2((p.x >> 16) | (p.y & 0xffff0000u),
                      (p.z >> 16) | (p.w & 0xffff0000u));
}

// bf16-truncate pack of 4 exp'd scores via 2x v_perm_b32 (bit-identical
// to 4x (short)(u>>16); verified r15, absmax unchanged).
__device__ inline short4v pack_pf(unsigned u0, unsigned u1,
                                  unsigned u2, unsigned u3) {
    uint2v pd;
    pd[0] = __builtin_amdgcn_perm(u1, u0, 0x07060302u);  // [u0.hi16 | u1.hi16<<16]
    pd[1] = __builtin_amdgcn_perm(u3, u2, 0x07060302u);
    return __builtin_bit_cast(short4v, pd);
}

// r16: native gfx950 16x16x32 bf16 MFMA (the _1k K=16 op is half-rate on
// CDNA4). A/B loaded with the SAME per-lane k-mapping (k4*32+quad*8+j) —
// contraction-sum-immune, so exact k-layout doesn't matter; C/D layout is
// identical to 16x16x16 (row=quad*4+reg, col=l).
__device__ inline float4v mfma32(short8v a, short8v b, float4v c) {
    return __builtin_amdgcn_mfma_f32_16x16x32_bf16(
        __builtin_bit_cast(bf16x8, a), __builtin_bit_cast(bf16x8, b), c, 0, 0, 0);
}

// Load a wave's W^T A-frags (16 co x 128 k) from global W[k][co] as FOUR
// K=32 fragments, split to bf16 hi/lo in-register. Weights L2/L3-hot.
__device__ inline void load_wfrags32(const float* __restrict__ W, int co0, int l,
                                     int quad, short8v* ah, short8v* al)
{
#pragma unroll
    for (int k4 = 0; k4 < 4; ++k4) {
#pragma unroll
        for (int j = 0; j < 8; ++j) {
            float w = W[(size_t)(k4 * 32 + quad * 8 + j) * CC + co0 + l];
            unsigned h = bf16rne(w);
            ah[k4][j] = (short)h;
            al[k4][j] = (short)bf16rne(w - bf2f(h));
        }
    }
}

#define AST 136   // LDS act row stride (ushorts); 136 -> ds_read_b128 16B-aligned

// ---------------------------------------------------------------------------
// Kernel 1: Q projection, BOTH branches per block (x staged once).
// r16: 16x16x32 MFMAs — 96 per block (was 192 at half-rate K=16), 32
// ds_read_b128 (was 64 b64). 64-token tiles, grid 496, LB(512,4).
// ---------------------------------------------------------------------------
__global__ __launch_bounds__(512, 4) void qproj_kernel(
    const float* __restrict__ x,
    const float* __restrict__ Wq1, const float* __restrict__ Wq2,
    const float* __restrict__ bq1, const float* __restrict__ bq2,
    unsigned* __restrict__ q1p, unsigned* __restrict__ q2p,
    float* __restrict__ sums)
{
    __shared__ ushort sbuf[2 * QTOK * AST];   // 34.8 KB: x hi/lo, then out staging
    ushort* Ahi = sbuf;
    ushort* Alo = sbuf + QTOK * AST;
    unsigned* S = (unsigned*)sbuf;            // 64 x 136 dwords (exact fit)
    const int tid = threadIdx.x;
    const int t0  = blockIdx.x * QTOK;
    if (blockIdx.x == 0 && tid < 2 * CC) sums[tid] = 0.f;   // for attn's atomics

    // stage x tile transposed + split: [t][ci] (once, shared by both branches)
    for (int i = tid; i < CC * QTOK / 4; i += 512) {
        int t4 = i & 15, ci = i >> 4;
        float4 v = *(const float4*)&x[(size_t)ci * TOK + t0 + t4 * 4];
        float xv[4] = {v.x, v.y, v.z, v.w};
#pragma unroll
        for (int e = 0; e < 4; ++e) {
            unsigned h = bf16rne(xv[e]);
            unsigned lw = bf16rne(xv[e] - bf2f(h));
            Ahi[(t4 * 4 + e) * AST + ci] = (ushort)h;
            Alo[(t4 * 4 + e) * AST + ci] = (ushort)lw;
        }
    }
    __syncthreads();

    const int lane = tid & 63;
    const int l    = lane & 15;
    const int quad = lane >> 4;
    const int co0  = (tid >> 6) * 16;

    // weight frags for BOTH branches live; one shared pass over LDS B-frags
    short8v ah[2][4], al[2][4];
    load_wfrags32(Wq1, co0, l, quad, ah[0], al[0]);
    load_wfrags32(Wq2, co0, l, quad, ah[1], al[1]);
    float4v acc[2][4];
#pragma unroll
    for (int br = 0; br < 2; ++br)
#pragma unroll
        for (int nt = 0; nt < 4; ++nt) acc[br][nt] = (float4v){0.f, 0.f, 0.f, 0.f};
#pragma unroll
    for (int k4 = 0; k4 < 4; ++k4) {
#pragma unroll
        for (int nt = 0; nt < 4; ++nt) {
            short8v bh = *(const short8v*)&Ahi[(nt * 16 + l) * AST + k4 * 32 + quad * 8];
            short8v bl = *(const short8v*)&Alo[(nt * 16 + l) * AST + k4 * 32 + quad * 8];
            acc[0][nt] = mfma32(ah[0][k4], bh, acc[0][nt]);
            acc[0][nt] = mfma32(ah[0][k4], bl, acc[0][nt]);
            acc[0][nt] = mfma32(al[0][k4], bh, acc[0][nt]);
            acc[1][nt] = mfma32(ah[1][k4], bh, acc[1][nt]);
            acc[1][nt] = mfma32(ah[1][k4], bl, acc[1][nt]);
            acc[1][nt] = mfma32(al[1][k4], bh, acc[1][nt]);
        }
    }

    // staged epilogues: LDS tile then contiguous full-line stores
    for (int branch = 0; branch < 2; ++branch) {
        const float* bq = branch ? bq2 : bq1;
        unsigned* op    = branch ? q2p : q1p;
        float4 bv = *(const float4*)&bq[co0 + quad * 4];
        float bb[4] = {bv.x, bv.y, bv.z, bv.w};
        __syncthreads();   // previous use of sbuf done
#pragma unroll
        for (int nt = 0; nt < 4; ++nt) {
#pragma unroll
            for (int reg = 0; reg < 4; ++reg)
                S[(nt * 16 + l) * AST + co0 + quad * 4 + reg] =
                    packsplit(acc[branch][nt][reg] + bb[reg]);
        }
        __syncthreads();
        for (int i = tid; i < QTOK * 32; i += 512) {
            int t = i >> 5, c4 = i & 31;
            uint4 pv = *(const uint4*)&S[t * AST + c4 * 4];
            *(uint4*)&op[(size_t)(t0 + t) * CC + c4 * 4] = pv;   // 512 B/32 lanes
        }
    }
}

// ---------------------------------------------------------------------------
// Kernel 2: FUSED attention, grid 248 (r14 structure, reverted from r15's
// query-split: the split doubled key staging — FETCH 23.9->39.7 MB — and
// regressed 59->70 µs; staging work dominates, occupancy wasn't the binding
// constraint). Phase 1 spatial computes O^T = V^T·P^T in-place on q2p;
// rowsums via ones-MFMA. Phase 2: spectral jobs. pack_pf (v_perm) kept.
// Attn contraction dims are structurally K=16 -> stays on the _1k op.
// ---------------------------------------------------------------------------
#define QS2 132
#define QSS 20
#define QTP 1044
__global__ __launch_bounds__(1024, 4) void attn_kernel(
    unsigned* __restrict__ q1p, unsigned* __restrict__ q2p,
    float* __restrict__ sums)
{
    __shared__ __align__(16) ushort smem[HWW * QSS + HD * QTP];  // 74.4 KB
    __shared__ float fsum[CC];
    const int tid  = threadIdx.x;
    const int lane = tid & 63;
    const int l    = lane & 15;
    const int quad = lane >> 4;
    const float k2 = SCALE2 * 1.44269504f;
    const short4v onesb = {(short)0x3F80, (short)0x3F80, (short)0x3F80, (short)0x3F80};
    if (tid < CC) fsum[tid] = 0.f;

    // ---------------- phase 1: spatial slice (O^T form) ----------------
    {
        const int d = blockIdx.x >> 3, h = blockIdx.x & 7;
        ushort* Qs  = smem;
        ushort* QTs = smem + HWW * QSS;
        const size_t base = (size_t)d * HWW * CC + h * HD;   // dword index

        for (int i = tid; i < HWW * 4; i += 1024) {
            int row = i >> 2, q4 = i & 3;
            uint4 p = *(const uint4*)&q2p[base + (size_t)row * CC + q4 * 4];
            *(uint2*)&Qs[row * QSS + q4 * 4] = pack_hi4(p);
            QTs[(q4 * 4 + 0) * QTP + row] = (ushort)p.x;
            QTs[(q4 * 4 + 1) * QTP + row] = (ushort)p.y;
            QTs[(q4 * 4 + 2) * QTP + row] = (ushort)p.z;
            QTs[(q4 * 4 + 3) * QTP + row] = (ushort)p.w;
        }
        __syncthreads();

        const int Rw = (tid >> 6) * 64;
        short4v qf[4];
#pragma unroll
        for (int lt = 0; lt < 4; ++lt) {
            short4v raw = *(short4v*)&Qs[(Rw + lt * 16 + l) * QSS + quad * 4];
            short4v sc;
#pragma unroll
            for (int e = 0; e < 4; ++e) {
                float f = bf2f((unsigned)(ushort)raw[e]) * k2;
                sc[e] = (short)bf16rne(f);
            }
            qf[lt] = sc;
        }

        float4v acc[4], accs[4];
#pragma unroll
        for (int lt = 0; lt < 4; ++lt) {
            acc[lt]  = (float4v){0.f, 0.f, 0.f, 0.f};
            accs[lt] = (float4v){0.f, 0.f, 0.f, 0.f};
        }

#pragma unroll 2
        for (int mt = 0; mt < 64; ++mt) {
            const int m0 = mt * 16;
            short4v ka = *(short4v*)&Qs[(m0 + l) * QSS + quad * 4];
            short4v vb = *(short4v*)&QTs[l * QTP + m0 + quad * 4];   // V^T A-frag
#pragma unroll
            for (int lt = 0; lt < 4; ++lt) {
                float4v s = __builtin_amdgcn_mfma_f32_16x16x16bf16_1k(
                    ka, qf[lt], (float4v){0.f, 0.f, 0.f, 0.f}, 0, 0, 0);
                unsigned u0 = __float_as_uint(__builtin_amdgcn_exp2f(s[0]));
                unsigned u1 = __float_as_uint(__builtin_amdgcn_exp2f(s[1]));
                unsigned u2 = __float_as_uint(__builtin_amdgcn_exp2f(s[2]));
                unsigned u3 = __float_as_uint(__builtin_amdgcn_exp2f(s[3]));
                short4v pf = pack_pf(u0, u1, u2, u3);
                // O^T[channel][query] += V^T · P^T ; denom via A=ones
                acc[lt]  = __builtin_amdgcn_mfma_f32_16x16x16bf16_1k(vb, pf, acc[lt], 0, 0, 0);
                accs[lt] = __builtin_amdgcn_mfma_f32_16x16x16bf16_1k(onesb, pf, accs[lt], 0, 0, 0);
            }
        }

        float vsum[4] = {0.f, 0.f, 0.f, 0.f};
#pragma unroll
        for (int lt = 0; lt < 4; ++lt) {
            float inv = 1.f / accs[lt][0];   // denom(query = Rw+lt*16+l); rows equal
            int token = Rw + lt * 16 + l;
            float v0 = acc[lt][0] * inv, v1 = acc[lt][1] * inv;
            float v2 = acc[lt][2] * inv, v3 = acc[lt][3] * inv;
            uint4 pv;
            pv.x = packsplit(v0); pv.y = packsplit(v1);
            pv.z = packsplit(v2); pv.w = packsplit(v3);
            *(uint4*)&q2p[base + (size_t)token * CC + quad * 4] = pv;
            vsum[0] += v0; vsum[1] += v1; vsum[2] += v2; vsum[3] += v3;
        }
#pragma unroll
        for (int reg = 0; reg < 4; ++reg) {
            float v = vsum[reg];
            v += __shfl_xor(v, 1); v += __shfl_xor(v, 2);
            v += __shfl_xor(v, 4); v += __shfl_xor(v, 8);
            if (l == 0) atomicAdd(&fsum[quad * 4 + reg], v);
        }
        __syncthreads();
        if (tid < HD) atomicAdd(&sums[CC + h * HD + tid], fsum[tid]);
    }

    // ---------------- phase 2: spectral job (if assigned) ----------------
    const int half_id = blockIdx.x >> 1;
    const bool has_job = (blockIdx.x & 1) ? (half_id < 4) : (half_id < 124);
    if (!has_job) return;
    const int job = (blockIdx.x & 1) ? (124 + half_id) : half_id;
    const int hw0 = job * 8;

    __syncthreads();                       // phase-1 smem reads + fsum use done
    if (tid < CC) fsum[tid] = 0.f;

    const int wave = tid >> 6;
    const int hwl  = wave >> 1;
    const int half = wave & 1;
    const int hw   = hw0 + hwl;
    ushort* Q = smem + hwl * (32 * QS2);
    for (int it = 0; it < 8; ++it) {
        int idx = it * 64 + lane;
        int dd = half * 16 + (idx >> 5), c4 = idx & 31;
        if (dd < 31) {
            uint4 p = *(const uint4*)&q1p[((size_t)dd * HWW + hw) * CC + c4 * 4];
            *(uint2*)&Q[dd * QS2 + c4 * 4] = pack_hi4(p);
        }
    }
    if (half) for (int i = lane; i < 128; i += 64) Q[31 * QS2 + i] = 0;
    __syncthreads();

    const int hh = half * 4;
#pragma unroll
    for (int hl = 0; hl < 4; ++hl) {
        const int hc = (hh + hl) * HD;
        short4v qf[2];
        qf[0] = *(const short4v*)&Q[l * QS2 + hc + quad * 4];
        qf[1] = *(const short4v*)&Q[(16 + l) * QS2 + hc + quad * 4];
        short4v va[2];
#pragma unroll
        for (int j = 0; j < 2; ++j)
#pragma unroll
            for (int jj = 0; jj < 4; ++jj)
                va[j][jj] = (short)Q[(j * 16 + quad * 4 + jj) * QS2 + hc + l];

        float4v o[2]   = {(float4v){0.f,0.f,0.f,0.f}, (float4v){0.f,0.f,0.f,0.f}};
        float4v osr[2] = {(float4v){0.f,0.f,0.f,0.f}, (float4v){0.f,0.f,0.f,0.f}};
#pragma unroll
        for (int j = 0; j < 2; ++j) {
#pragma unroll
            for (int i2 = 0; i2 < 2; ++i2) {
                float4v s = __builtin_amdgcn_mfma_f32_16x16x16bf16_1k(
                    qf[j], qf[i2], (float4v){0.f,0.f,0.f,0.f}, 0, 0, 0);
                unsigned u0 = __float_as_uint(__builtin_amdgcn_exp2f(s[0] * k2));
                unsigned u1 = __float_as_uint(__builtin_amdgcn_exp2f(s[1] * k2));
                unsigned u2 = __float_as_uint(__builtin_amdgcn_exp2f(s[2] * k2));
                unsigned u3 = __float_as_uint(__builtin_amdgcn_exp2f(s[3] * k2));
                if (j == 1 && quad == 3) u3 = 0;   // mask key 31
                short4v pf = pack_pf(u0, u1, u2, u3);
                o[i2]   = __builtin_amdgcn_mfma_f32_16x16x16bf16_1k(va[j], pf, o[i2], 0, 0, 0);
                osr[i2] = __builtin_amdgcn_mfma_f32_16x16x16bf16_1k(onesb, pf, osr[i2], 0, 0, 0);
            }
        }
        float vsum[4] = {0.f, 0.f, 0.f, 0.f};
#pragma unroll
        for (int i2 = 0; i2 < 2; ++i2) {
            float inv = 1.f / osr[i2][0];   // rowsum(query=i2*16+l), this lane
            int dq = i2 * 16 + l;
            if (dq < 31) {
                uint4 pv;
                float v0 = o[i2][0] * inv, v1 = o[i2][1] * inv;
                float v2 = o[i2][2] * inv, v3 = o[i2][3] * inv;
                pv.x = packsplit(v0); pv.y = packsplit(v1);
                pv.z = packsplit(v2); pv.w = packsplit(v3);
                *(uint4*)&q1p[((size_t)dq * HWW + hw) * CC + hc + quad * 4] = pv;
                vsum[0] += v0; vsum[1] += v1; vsum[2] += v2; vsum[3] += v3;
            }
        }
#pragma unroll
        for (int r = 0; r < 4; ++r) {
            float v = vsum[r];
            v += __shfl_xor(v, 1); v += __shfl_xor(v, 2);
            v += __shfl_xor(v, 4); v += __shfl_xor(v, 8);
            if (l == 0) atomicAdd(&fsum[hc + quad * 4 + r], v);
        }
    }
    __syncthreads();
    if (tid < CC) atomicAdd(&sums[tid], fsum[tid]);
}

// ---------------------------------------------------------------------------
// Kernel 3: output projection + in-block gate, BOTH branches, 64-token tiles.
// r16: 16x16x32 MFMAs (96/block, was 192 half-rate) + ds_read_b128 B-frags.
// ---------------------------------------------------------------------------
__global__ __launch_bounds__(512, 4) void oproj_kernel(
    const unsigned* __restrict__ q1p, const unsigned* __restrict__ q2p,
    const float* __restrict__ Wp1, const float* __restrict__ Wp2,
    const float* __restrict__ bp1, const float* __restrict__ bp2,
    const float* __restrict__ Wg,  const float* __restrict__ bg,
    const float* __restrict__ sums, float* __restrict__ out)
{
    __shared__ ushort sbuf[2 * 64 * AST];   // 34.8 KB: act hi/lo, then out staging
    ushort* Ahi = sbuf;
    ushort* Alo = sbuf + 64 * AST;
    unsigned* S = (unsigned*)sbuf;          // 128 x 66 dwords
    __shared__ float pa[4][CC];
    __shared__ float giv[2 * CC];
    __shared__ float gf[CC];
    const int tid = threadIdx.x;
    const int t0  = blockIdx.x * 64;
    const int lane = tid & 63;
    const int l    = lane & 15;
    const int quad = lane >> 4;
    const int co0  = (tid >> 6) * 16;

    // ---- gate phase (two-stage GEMV from sums; exact reference math) ----
    {
        const int part = tid >> 7, c = tid & 127;
        const float* Wp = (part < 2) ? Wp1 : Wp2;
        const float* sp = (part < 2) ? sums : sums + CC;
        const int k0 = (part & 1) * 64;
        float a = 0.f;
        for (int kk = 0; kk < 64; ++kk) {
            int k = k0 + kk;
            a += sp[k] * Wp[(size_t)k * CC + c];
        }
        pa[part][c] = a;
        __syncthreads();
        if (tid < 2 * CC) {
            float m = (tid < CC) ? (pa[0][tid] + pa[1][tid])
                                 : (pa[2][tid - CC] + pa[3][tid - CC]);
            float bb = (tid < CC) ? bp1[tid] : bp2[tid - CC];
            giv[tid] = m * (1.f / (float)TOK) + bb;
        }
        __syncthreads();
        float b = 0.f;
        for (int kk = 0; kk < 64; ++kk) {
            int j = part * 64 + kk;
            b += giv[j] * Wg[(size_t)j * CC + c];
        }
        pa[part][c] = b;
        __syncthreads();
        if (tid < CC)
            gf[tid] = 1.f / (1.f + __expf(-(bg[tid] + pa[0][tid] + pa[1][tid] +
                                           pa[2][tid] + pa[3][tid])));
    }

    // ---- main GEMM ----
    float4v acc[2][4];
#pragma unroll
    for (int br = 0; br < 2; ++br)
#pragma unroll
        for (int nt = 0; nt < 4; ++nt) acc[br][nt] = (float4v){0.f, 0.f, 0.f, 0.f};

    for (int br = 0; br < 2; ++br) {
        const unsigned* Ap = br ? q2p : q1p;
        const float*    W  = br ? Wp2 : Wp1;
        short8v ah[4], al[4];
        load_wfrags32(W, co0, l, quad, ah, al);
        __syncthreads();   // previous phase/branch LDS reads done
        for (int i = tid; i < 64 * 32; i += 512) {
            int t = i >> 5, c4 = i & 31;
            uint4 p = *(const uint4*)&Ap[(size_t)(t0 + t) * CC + c4 * 4];
            *(uint2*)&Ahi[t * AST + c4 * 4] = pack_hi4(p);
            *(uint2*)&Alo[t * AST + c4 * 4] = pack_lo4(p);
        }
        __syncthreads();
#pragma unroll
        for (int k4 = 0; k4 < 4; ++k4) {
#pragma unroll
            for (int nt = 0; nt < 4; ++nt) {
                short8v bh = *(const short8v*)&Ahi[(nt * 16 + l) * AST + k4 * 32 + quad * 8];
                short8v bl = *(const short8v*)&Alo[(nt * 16 + l) * AST + k4 * 32 + quad * 8];
                acc[br][nt] = mfma32(ah[k4], bh, acc[br][nt]);
                acc[br][nt] = mfma32(ah[k4], bl, acc[br][nt]);
                acc[br][nt] = mfma32(al[k4], bh, acc[br][nt]);
            }
        }
    }

    float4 b1 = *(const float4*)&bp1[co0 + quad * 4];
    float4 b2 = *(const float4*)&bp2[co0 + quad * 4];
    float bb1[4] = {b1.x, b1.y, b1.z, b1.w};
    float bb2[4] = {b2.x, b2.y, b2.z, b2.w};
    float gg[4];
#pragma unroll
    for (int e = 0; e < 4; ++e) gg[e] = gf[co0 + quad * 4 + e];

    // staged epilogue: [co][t] tile in LDS (stride 66), then contiguous stores
    __syncthreads();   // act LDS reads done
#pragma unroll
    for (int nt = 0; nt < 4; ++nt) {
        int tl = nt * 16 + l;
#pragma unroll
        for (int reg = 0; reg < 4; ++reg) {
            float v = gg[reg] * (acc[0][nt][reg] + bb1[reg]) +
                      (1.f - gg[reg]) * (acc[1][nt][reg] + bb2[reg]);
            S[(co0 + quad * 4 + reg) * 66 + tl] = __float_as_uint(v);
        }
    }
    __syncthreads();
    for (int i = tid; i < 128 * 32; i += 512) {
        int co = i >> 5, t2 = i & 31;
        uint2 v = *(const uint2*)&S[co * 66 + t2 * 2];
        *(uint2*)&out[(size_t)co * TOK + t0 + t2 * 2] = v;   // 256 B/32 lanes
    }
}

extern "C" void kernel_launch(void* const* d_in, const int* in_sizes, int n_in,
                              void* d_out, int out_size, void* d_ws, size_t ws_size,
                              hipStream_t stream)
{
    const float* x   = (const float*)d_in[0];
    const float* Wq1 = (const float*)d_in[1];
    const float* bq1 = (const float*)d_in[2];
    const float* Wp1 = (const float*)d_in[3];
    const float* bp1 = (const float*)d_in[4];
    const float* Wq2 = (const float*)d_in[5];
    const float* bq2 = (const float*)d_in[6];
    const float* Wp2 = (const float*)d_in[7];
    const float* bp2 = (const float*)d_in[8];
    const float* Wg  = (const float*)d_in[9];
    const float* bg  = (const float*)d_in[10];
    float* out = (float*)d_out;

    const size_t plane = (size_t)TOK * CC;             // dwords per packed plane
    unsigned* q1p = (unsigned*)d_ws;
    unsigned* q2p = q1p + plane;
    float*   sums = (float*)(q2p + plane);             // 256 floats (zeroed by qproj)

    qproj_kernel<<<dim3(TOK / QTOK), 512, 0, stream>>>(x, Wq1, Wq2, bq1, bq2,
                                                       q1p, q2p, sums);
    attn_kernel<<<dim3(248), 1024, 0, stream>>>(q1p, q2p, sums);
    oproj_kernel<<<dim3(496), 512, 0, stream>>>(q1p, q2p,
                                                Wp1, Wp2, bp1, bp2, Wg, bg,
                                                sums, out);
}

// Round 3
// 170.407 us; speedup vs baseline: 1.0641x; 1.0155x over previous
//
#include <hip/hip_runtime.h>
#include <cstddef>

#define CC 128
#define NH 8
#define HD 16
#define DDIM 31
#define HWW 1024
#define TOK 31744   // DDIM * HWW
#define SCALE2 0.0625f   // (HD^-0.5)^2 — both QK^T operands pre-scaled in the ref
#define QTOK 64     // qproj token tile (grid 496 -> 2 blocks/CU)

typedef __attribute__((ext_vector_type(4))) short  short4v;
typedef __attribute__((ext_vector_type(8))) short  short8v;
typedef __attribute__((ext_vector_type(4))) float  float4v;
typedef __attribute__((ext_vector_type(2))) unsigned uint2v;
typedef __attribute__((ext_vector_type(4))) unsigned uint4v;
typedef __attribute__((ext_vector_type(8))) __bf16 bf16x8;

__device__ inline unsigned bf16rne(float f) {
    unsigned u = __float_as_uint(f);
    return (u + 0x7fffu + ((u >> 16) & 1u)) >> 16;
}
__device__ inline float bf2f(unsigned h) { return __uint_as_float(h << 16); }

// Packed activation element: dword = hi_bf16 | (lo_bf16 << 16).
__device__ inline unsigned packsplit(float v) {
    unsigned h = bf16rne(v);
    unsigned l = bf16rne(v - bf2f(h));
    return h | (l << 16);
}
__device__ inline uint2 pack_hi4(uint4 p) {
    return make_uint2((p.x & 0xffffu) | (p.y << 16),
                      (p.z & 0xffffu) | (p.w << 16));
}
__device__ inline uint2 pack_lo4(uint4 p) {
    return make_uint2((p.x >> 16) | (p.y & 0xffff0000u),
                      (p.z >> 16) | (p.w & 0xffff0000u));
}

// bf16-truncate pack of 8 exp'd scores via 4x v_perm_b32 (bit-identical to
// (short)(u>>16) per element; perm pattern verified r15/r16).
__device__ inline short8v pack_pf8(unsigned u0, unsigned u1, unsigned u2,
                                   unsigned u3, unsigned u4, unsigned u5,
                                   unsigned u6, unsigned u7) {
    uint4v pd;
    pd[0] = __builtin_amdgcn_perm(u1, u0, 0x07060302u);  // [u0.hi16 | u1.hi16<<16]
    pd[1] = __builtin_amdgcn_perm(u3, u2, 0x07060302u);
    pd[2] = __builtin_amdgcn_perm(u5, u4, 0x07060302u);
    pd[3] = __builtin_amdgcn_perm(u7, u6, 0x07060302u);
    return __builtin_bit_cast(short8v, pd);
}

// Native gfx950 16x16x32 bf16 MFMA (full rate; the _1k K=16 op is half-rate
// on CDNA4). A/B built with the SAME per-lane k-mapping — contraction-sum-
// immune; C/D layout identical to 16x16x16 (row=quad*4+reg, col=l).
__device__ inline float4v mfma32(short8v a, short8v b, float4v c) {
    return __builtin_amdgcn_mfma_f32_16x16x32_bf16(
        __builtin_bit_cast(bf16x8, a), __builtin_bit_cast(bf16x8, b), c, 0, 0, 0);
}
__device__ inline float4v mfma16(short4v a, short4v b) {
    return __builtin_amdgcn_mfma_f32_16x16x16bf16_1k(
        a, b, (float4v){0.f, 0.f, 0.f, 0.f}, 0, 0, 0);
}

// Load a wave's W^T A-frags (16 co x 128 k) from global W[k][co] as FOUR
// K=32 fragments, split to bf16 hi/lo in-register. Weights L2/L3-hot.
__device__ inline void load_wfrags32(const float* __restrict__ W, int co0, int l,
                                     int quad, short8v* ah, short8v* al)
{
#pragma unroll
    for (int k4 = 0; k4 < 4; ++k4) {
#pragma unroll
        for (int j = 0; j < 8; ++j) {
            float w = W[(size_t)(k4 * 32 + quad * 8 + j) * CC + co0 + l];
            unsigned h = bf16rne(w);
            ah[k4][j] = (short)h;
            al[k4][j] = (short)bf16rne(w - bf2f(h));
        }
    }
}

#define AST 136   // LDS act row stride (ushorts); 136 -> ds_read_b128 16B-aligned

// ---------------------------------------------------------------------------
// Kernel 1: Q projection, BOTH branches per block (x staged once).
// r17: staging re-indexed — each thread owns (token, 4 channels): coalesced
// scalar global reads + 2x ds_write_b64 (was 8x 8-way-conflicted b16 writes).
// ---------------------------------------------------------------------------
__global__ __launch_bounds__(512, 4) void qproj_kernel(
    const float* __restrict__ x,
    const float* __restrict__ Wq1, const float* __restrict__ Wq2,
    const float* __restrict__ bq1, const float* __restrict__ bq2,
    unsigned* __restrict__ q1p, unsigned* __restrict__ q2p,
    float* __restrict__ sums)
{
    __shared__ ushort sbuf[2 * QTOK * AST];   // 34.8 KB: x hi/lo, then out staging
    ushort* Ahi = sbuf;
    ushort* Alo = sbuf + QTOK * AST;
    unsigned* S = (unsigned*)sbuf;            // 64 x 136 dwords (exact fit)
    const int tid = threadIdx.x;
    const int t0  = blockIdx.x * QTOK;
    if (blockIdx.x == 0 && tid < 2 * CC) sums[tid] = 0.f;   // for attn's atomics

    // stage x tile transposed + split: [t][ci] (once, shared by both branches)
    for (int i = tid; i < QTOK * 32; i += 512) {
        int t = i & 63, c4 = i >> 6;          // lanes: consecutive t -> coalesced
        unsigned hw[2], lw[2];
#pragma unroll
        for (int p = 0; p < 2; ++p) {
            unsigned h0, l0, h1, l1;
            {
                float v = x[(size_t)(c4 * 4 + p * 2 + 0) * TOK + t0 + t];
                h0 = bf16rne(v); l0 = bf16rne(v - bf2f(h0));
            }
            {
                float v = x[(size_t)(c4 * 4 + p * 2 + 1) * TOK + t0 + t];
                h1 = bf16rne(v); l1 = bf16rne(v - bf2f(h1));
            }
            hw[p] = h0 | (h1 << 16);
            lw[p] = l0 | (l1 << 16);
        }
        *(uint2*)&Ahi[t * AST + c4 * 4] = make_uint2(hw[0], hw[1]);
        *(uint2*)&Alo[t * AST + c4 * 4] = make_uint2(lw[0], lw[1]);
    }
    __syncthreads();

    const int lane = tid & 63;
    const int l    = lane & 15;
    const int quad = lane >> 4;
    const int co0  = (tid >> 6) * 16;

    // weight frags for BOTH branches live; one shared pass over LDS B-frags
    short8v ah[2][4], al[2][4];
    load_wfrags32(Wq1, co0, l, quad, ah[0], al[0]);
    load_wfrags32(Wq2, co0, l, quad, ah[1], al[1]);
    float4v acc[2][4];
#pragma unroll
    for (int br = 0; br < 2; ++br)
#pragma unroll
        for (int nt = 0; nt < 4; ++nt) acc[br][nt] = (float4v){0.f, 0.f, 0.f, 0.f};
#pragma unroll
    for (int k4 = 0; k4 < 4; ++k4) {
#pragma unroll
        for (int nt = 0; nt < 4; ++nt) {
            short8v bh = *(const short8v*)&Ahi[(nt * 16 + l) * AST + k4 * 32 + quad * 8];
            short8v bl = *(const short8v*)&Alo[(nt * 16 + l) * AST + k4 * 32 + quad * 8];
            acc[0][nt] = mfma32(ah[0][k4], bh, acc[0][nt]);
            acc[0][nt] = mfma32(ah[0][k4], bl, acc[0][nt]);
            acc[0][nt] = mfma32(al[0][k4], bh, acc[0][nt]);
            acc[1][nt] = mfma32(ah[1][k4], bh, acc[1][nt]);
            acc[1][nt] = mfma32(ah[1][k4], bl, acc[1][nt]);
            acc[1][nt] = mfma32(al[1][k4], bh, acc[1][nt]);
        }
    }

    // staged epilogues: LDS tile then contiguous full-line stores
    for (int branch = 0; branch < 2; ++branch) {
        const float* bq = branch ? bq2 : bq1;
        unsigned* op    = branch ? q2p : q1p;
        float4 bv = *(const float4*)&bq[co0 + quad * 4];
        float bb[4] = {bv.x, bv.y, bv.z, bv.w};
        __syncthreads();   // previous use of sbuf done
#pragma unroll
        for (int nt = 0; nt < 4; ++nt) {
#pragma unroll
            for (int reg = 0; reg < 4; ++reg)
                S[(nt * 16 + l) * AST + co0 + quad * 4 + reg] =
                    packsplit(acc[branch][nt][reg] + bb[reg]);
        }
        __syncthreads();
        for (int i = tid; i < QTOK * 32; i += 512) {
            int t = i >> 5, c4 = i & 31;
            uint4 pv = *(const uint4*)&S[t * AST + c4 * 4];
            *(uint4*)&op[(size_t)(t0 + t) * CC + c4 * 4] = pv;   // 512 B/32 lanes
        }
    }
}

// ---------------------------------------------------------------------------
// Kernel 2: FUSED attention, grid 248.
// r17: PV + ones-rowsum contract over the KEY axis (1024 / 31 long) — now
// chunked at 32 keys: two 16-key score tiles are exp'd, packed into one
// short8v, and fed to ONE full-rate 16x16x32 MFMA each (was 2+2 half-rate
// _1k). Same LDS read addresses; k-mapping shared by A and B so the sum is
// exact regardless of HW k-layout. QK^T stays _1k (structurally K=16).
// ---------------------------------------------------------------------------
#define QS2 132
#define QSS 20
#define QTP 1044
__global__ __launch_bounds__(1024, 4) void attn_kernel(
    unsigned* __restrict__ q1p, unsigned* __restrict__ q2p,
    float* __restrict__ sums)
{
    __shared__ __align__(16) ushort smem[HWW * QSS + HD * QTP];  // 74.4 KB
    __shared__ float fsum[CC];
    const int tid  = threadIdx.x;
    const int lane = tid & 63;
    const int l    = lane & 15;
    const int quad = lane >> 4;
    const float k2 = SCALE2 * 1.44269504f;
    const short8v ones8 = {(short)0x3F80, (short)0x3F80, (short)0x3F80, (short)0x3F80,
                           (short)0x3F80, (short)0x3F80, (short)0x3F80, (short)0x3F80};
    if (tid < CC) fsum[tid] = 0.f;

    // ---------------- phase 1: spatial slice (O^T form) ----------------
    {
        const int d = blockIdx.x >> 3, h = blockIdx.x & 7;
        ushort* Qs  = smem;
        ushort* QTs = smem + HWW * QSS;
        const size_t base = (size_t)d * HWW * CC + h * HD;   // dword index

        for (int i = tid; i < HWW * 4; i += 1024) {
            int row = i >> 2, q4 = i & 3;
            uint4 p = *(const uint4*)&q2p[base + (size_t)row * CC + q4 * 4];
            *(uint2*)&Qs[row * QSS + q4 * 4] = pack_hi4(p);
            QTs[(q4 * 4 + 0) * QTP + row] = (ushort)p.x;
            QTs[(q4 * 4 + 1) * QTP + row] = (ushort)p.y;
            QTs[(q4 * 4 + 2) * QTP + row] = (ushort)p.z;
            QTs[(q4 * 4 + 3) * QTP + row] = (ushort)p.w;
        }
        __syncthreads();

        const int Rw = (tid >> 6) * 64;
        short4v qf[4];
#pragma unroll
        for (int lt = 0; lt < 4; ++lt) {
            short4v raw = *(short4v*)&Qs[(Rw + lt * 16 + l) * QSS + quad * 4];
            short4v sc;
#pragma unroll
            for (int e = 0; e < 4; ++e) {
                float f = bf2f((unsigned)(ushort)raw[e]) * k2;
                sc[e] = (short)bf16rne(f);
            }
            qf[lt] = sc;
        }

        float4v acc[4], accs[4];
#pragma unroll
        for (int lt = 0; lt < 4; ++lt) {
            acc[lt]  = (float4v){0.f, 0.f, 0.f, 0.f};
            accs[lt] = (float4v){0.f, 0.f, 0.f, 0.f};
        }

        for (int mt2 = 0; mt2 < 32; ++mt2) {
            const int m0 = mt2 * 32;
            short4v ka0 = *(short4v*)&Qs[(m0 + l) * QSS + quad * 4];
            short4v ka1 = *(short4v*)&Qs[(m0 + 16 + l) * QSS + quad * 4];
            short4v v0  = *(short4v*)&QTs[l * QTP + m0 + quad * 4];
            short4v v1  = *(short4v*)&QTs[l * QTP + m0 + 16 + quad * 4];
            short8v vb  = __builtin_shufflevector(v0, v1, 0, 1, 2, 3, 4, 5, 6, 7);
#pragma unroll
            for (int lt = 0; lt < 4; ++lt) {
                float4v s0 = mfma16(ka0, qf[lt]);
                float4v s1 = mfma16(ka1, qf[lt]);
                unsigned u0 = __float_as_uint(__builtin_amdgcn_exp2f(s0[0]));
                unsigned u1 = __float_as_uint(__builtin_amdgcn_exp2f(s0[1]));
                unsigned u2 = __float_as_uint(__builtin_amdgcn_exp2f(s0[2]));
                unsigned u3 = __float_as_uint(__builtin_amdgcn_exp2f(s0[3]));
                unsigned u4 = __float_as_uint(__builtin_amdgcn_exp2f(s1[0]));
                unsigned u5 = __float_as_uint(__builtin_amdgcn_exp2f(s1[1]));
                unsigned u6 = __float_as_uint(__builtin_amdgcn_exp2f(s1[2]));
                unsigned u7 = __float_as_uint(__builtin_amdgcn_exp2f(s1[3]));
                short8v pf = pack_pf8(u0, u1, u2, u3, u4, u5, u6, u7);
                // O^T[channel][query] += V^T · P^T over 32 keys; denom via A=ones
                acc[lt]  = mfma32(vb, pf, acc[lt]);
                accs[lt] = mfma32(ones8, pf, accs[lt]);
            }
        }

        float vsum[4] = {0.f, 0.f, 0.f, 0.f};
#pragma unroll
        for (int lt = 0; lt < 4; ++lt) {
            float inv = 1.f / accs[lt][0];   // denom(query = Rw+lt*16+l); rows equal
            int token = Rw + lt * 16 + l;
            float v0 = acc[lt][0] * inv, v1 = acc[lt][1] * inv;
            float v2 = acc[lt][2] * inv, v3 = acc[lt][3] * inv;
            uint4 pv;
            pv.x = packsplit(v0); pv.y = packsplit(v1);
            pv.z = packsplit(v2); pv.w = packsplit(v3);
            *(uint4*)&q2p[base + (size_t)token * CC + quad * 4] = pv;
            vsum[0] += v0; vsum[1] += v1; vsum[2] += v2; vsum[3] += v3;
        }
#pragma unroll
        for (int reg = 0; reg < 4; ++reg) {
            float v = vsum[reg];
            v += __shfl_xor(v, 1); v += __shfl_xor(v, 2);
            v += __shfl_xor(v, 4); v += __shfl_xor(v, 8);
            if (l == 0) atomicAdd(&fsum[quad * 4 + reg], v);
        }
        __syncthreads();
        if (tid < HD) atomicAdd(&sums[CC + h * HD + tid], fsum[tid]);
    }

    // ---------------- phase 2: spectral job (if assigned) ----------------
    const int half_id = blockIdx.x >> 1;
    const bool has_job = (blockIdx.x & 1) ? (half_id < 4) : (half_id < 124);
    if (!has_job) return;
    const int job = (blockIdx.x & 1) ? (124 + half_id) : half_id;
    const int hw0 = job * 8;

    __syncthreads();                       // phase-1 smem reads + fsum use done
    if (tid < CC) fsum[tid] = 0.f;

    const int wave = tid >> 6;
    const int hwl  = wave >> 1;
    const int half = wave & 1;
    const int hw   = hw0 + hwl;
    ushort* Q = smem + hwl * (32 * QS2);
    for (int it = 0; it < 8; ++it) {
        int idx = it * 64 + lane;
        int dd = half * 16 + (idx >> 5), c4 = idx & 31;
        if (dd < 31) {
            uint4 p = *(const uint4*)&q1p[((size_t)dd * HWW + hw) * CC + c4 * 4];
            *(uint2*)&Q[dd * QS2 + c4 * 4] = pack_hi4(p);
        }
    }
    if (half) for (int i = lane; i < 128; i += 64) Q[31 * QS2 + i] = 0;
    __syncthreads();

    const int hh = half * 4;
#pragma unroll
    for (int hl = 0; hl < 4; ++hl) {
        const int hc = (hh + hl) * HD;
        short4v qf[2];
        qf[0] = *(const short4v*)&Q[l * QS2 + hc + quad * 4];
        qf[1] = *(const short4v*)&Q[(16 + l) * QS2 + hc + quad * 4];
        short8v va8;
#pragma unroll
        for (int jj = 0; jj < 4; ++jj) {
            va8[jj]     = (short)Q[(quad * 4 + jj) * QS2 + hc + l];
            va8[jj + 4] = (short)Q[(16 + quad * 4 + jj) * QS2 + hc + l];
        }

        float4v o[2]   = {(float4v){0.f,0.f,0.f,0.f}, (float4v){0.f,0.f,0.f,0.f}};
        float4v osr[2] = {(float4v){0.f,0.f,0.f,0.f}, (float4v){0.f,0.f,0.f,0.f}};
#pragma unroll
        for (int i2 = 0; i2 < 2; ++i2) {
            float4v s0 = mfma16(qf[0], qf[i2]);
            float4v s1 = mfma16(qf[1], qf[i2]);
            unsigned u0 = __float_as_uint(__builtin_amdgcn_exp2f(s0[0] * k2));
            unsigned u1 = __float_as_uint(__builtin_amdgcn_exp2f(s0[1] * k2));
            unsigned u2 = __float_as_uint(__builtin_amdgcn_exp2f(s0[2] * k2));
            unsigned u3 = __float_as_uint(__builtin_amdgcn_exp2f(s0[3] * k2));
            unsigned u4 = __float_as_uint(__builtin_amdgcn_exp2f(s1[0] * k2));
            unsigned u5 = __float_as_uint(__builtin_amdgcn_exp2f(s1[1] * k2));
            unsigned u6 = __float_as_uint(__builtin_amdgcn_exp2f(s1[2] * k2));
            unsigned u7 = __float_as_uint(__builtin_amdgcn_exp2f(s1[3] * k2));
            if (quad == 3) u7 = 0;   // mask key 31 (slot 16+quad*4+3)
            short8v pf = pack_pf8(u0, u1, u2, u3, u4, u5, u6, u7);
            o[i2]   = mfma32(va8, pf, o[i2]);
            osr[i2] = mfma32(ones8, pf, osr[i2]);
        }
        float vsum[4] = {0.f, 0.f, 0.f, 0.f};
#pragma unroll
        for (int i2 = 0; i2 < 2; ++i2) {
            float inv = 1.f / osr[i2][0];   // rowsum(query=i2*16+l), this lane
            int dq = i2 * 16 + l;
            if (dq < 31) {
                uint4 pv;
                float v0 = o[i2][0] * inv, v1 = o[i2][1] * inv;
                float v2 = o[i2][2] * inv, v3 = o[i2][3] * inv;
                pv.x = packsplit(v0); pv.y = packsplit(v1);
                pv.z = packsplit(v2); pv.w = packsplit(v3);
                *(uint4*)&q1p[((size_t)dq * HWW + hw) * CC + hc + quad * 4] = pv;
                vsum[0] += v0; vsum[1] += v1; vsum[2] += v2; vsum[3] += v3;
            }
        }
#pragma unroll
        for (int r = 0; r < 4; ++r) {
            float v = vsum[r];
            v += __shfl_xor(v, 1); v += __shfl_xor(v, 2);
            v += __shfl_xor(v, 4); v += __shfl_xor(v, 8);
            if (l == 0) atomicAdd(&fsum[hc + quad * 4 + r], v);
        }
    }
    __syncthreads();
    if (tid < CC) atomicAdd(&sums[tid], fsum[tid]);
}

// ---------------------------------------------------------------------------
// Kernel 3: output projection + in-block gate, BOTH branches, 64-token tiles.
// (r16 body unchanged: 16x16x32 MFMAs + ds_read_b128 B-frags.)
// ---------------------------------------------------------------------------
__global__ __launch_bounds__(512, 4) void oproj_kernel(
    const unsigned* __restrict__ q1p, const unsigned* __restrict__ q2p,
    const float* __restrict__ Wp1, const float* __restrict__ Wp2,
    const float* __restrict__ bp1, const float* __restrict__ bp2,
    const float* __restrict__ Wg,  const float* __restrict__ bg,
    const float* __restrict__ sums, float* __restrict__ out)
{
    __shared__ ushort sbuf[2 * 64 * AST];   // 34.8 KB: act hi/lo, then out staging
    ushort* Ahi = sbuf;
    ushort* Alo = sbuf + 64 * AST;
    unsigned* S = (unsigned*)sbuf;          // 128 x 66 dwords
    __shared__ float pa[4][CC];
    __shared__ float giv[2 * CC];
    __shared__ float gf[CC];
    const int tid = threadIdx.x;
    const int t0  = blockIdx.x * 64;
    const int lane = tid & 63;
    const int l    = lane & 15;
    const int quad = lane >> 4;
    const int co0  = (tid >> 6) * 16;

    // ---- gate phase (two-stage GEMV from sums; exact reference math) ----
    {
        const int part = tid >> 7, c = tid & 127;
        const float* Wp = (part < 2) ? Wp1 : Wp2;
        const float* sp = (part < 2) ? sums : sums + CC;
        const int k0 = (part & 1) * 64;
        float a = 0.f;
        for (int kk = 0; kk < 64; ++kk) {
            int k = k0 + kk;
            a += sp[k] * Wp[(size_t)k * CC + c];
        }
        pa[part][c] = a;
        __syncthreads();
        if (tid < 2 * CC) {
            float m = (tid < CC) ? (pa[0][tid] + pa[1][tid])
                                 : (pa[2][tid - CC] + pa[3][tid - CC]);
            float bb = (tid < CC) ? bp1[tid] : bp2[tid - CC];
            giv[tid] = m * (1.f / (float)TOK) + bb;
        }
        __syncthreads();
        float b = 0.f;
        for (int kk = 0; kk < 64; ++kk) {
            int j = part * 64 + kk;
            b += giv[j] * Wg[(size_t)j * CC + c];
        }
        pa[part][c] = b;
        __syncthreads();
        if (tid < CC)
            gf[tid] = 1.f / (1.f + __expf(-(bg[tid] + pa[0][tid] + pa[1][tid] +
                                           pa[2][tid] + pa[3][tid])));
    }

    // ---- main GEMM ----
    float4v acc[2][4];
#pragma unroll
    for (int br = 0; br < 2; ++br)
#pragma unroll
        for (int nt = 0; nt < 4; ++nt) acc[br][nt] = (float4v){0.f, 0.f, 0.f, 0.f};

    for (int br = 0; br < 2; ++br) {
        const unsigned* Ap = br ? q2p : q1p;
        const float*    W  = br ? Wp2 : Wp1;
        short8v ah[4], al[4];
        load_wfrags32(W, co0, l, quad, ah, al);
        __syncthreads();   // previous phase/branch LDS reads done
        for (int i = tid; i < 64 * 32; i += 512) {
            int t = i >> 5, c4 = i & 31;
            uint4 p = *(const uint4*)&Ap[(size_t)(t0 + t) * CC + c4 * 4];
            *(uint2*)&Ahi[t * AST + c4 * 4] = pack_hi4(p);
            *(uint2*)&Alo[t * AST + c4 * 4] = pack_lo4(p);
        }
        __syncthreads();
#pragma unroll
        for (int k4 = 0; k4 < 4; ++k4) {
#pragma unroll
            for (int nt = 0; nt < 4; ++nt) {
                short8v bh = *(const short8v*)&Ahi[(nt * 16 + l) * AST + k4 * 32 + quad * 8];
                short8v bl = *(const short8v*)&Alo[(nt * 16 + l) * AST + k4 * 32 + quad * 8];
                acc[br][nt] = mfma32(ah[k4], bh, acc[br][nt]);
                acc[br][nt] = mfma32(ah[k4], bl, acc[br][nt]);
                acc[br][nt] = mfma32(al[k4], bh, acc[br][nt]);
            }
        }
    }

    float4 b1 = *(const float4*)&bp1[co0 + quad * 4];
    float4 b2 = *(const float4*)&bp2[co0 + quad * 4];
    float bb1[4] = {b1.x, b1.y, b1.z, b1.w};
    float bb2[4] = {b2.x, b2.y, b2.z, b2.w};
    float gg[4];
#pragma unroll
    for (int e = 0; e < 4; ++e) gg[e] = gf[co0 + quad * 4 + e];

    // staged epilogue: [co][t] tile in LDS (stride 66), then contiguous stores
    __syncthreads();   // act LDS reads done
#pragma unroll
    for (int nt = 0; nt < 4; ++nt) {
        int tl = nt * 16 + l;
#pragma unroll
        for (int reg = 0; reg < 4; ++reg) {
            float v = gg[reg] * (acc[0][nt][reg] + bb1[reg]) +
                      (1.f - gg[reg]) * (acc[1][nt][reg] + bb2[reg]);
            S[(co0 + quad * 4 + reg) * 66 + tl] = __float_as_uint(v);
        }
    }
    __syncthreads();
    for (int i = tid; i < 128 * 32; i += 512) {
        int co = i >> 5, t2 = i & 31;
        uint2 v = *(const uint2*)&S[co * 66 + t2 * 2];
        *(uint2*)&out[(size_t)co * TOK + t0 + t2 * 2] = v;   // 256 B/32 lanes
    }
}

extern "C" void kernel_launch(void* const* d_in, const int* in_sizes, int n_in,
                              void* d_out, int out_size, void* d_ws, size_t ws_size,
                              hipStream_t stream)
{
    const float* x   = (const float*)d_in[0];
    const float* Wq1 = (const float*)d_in[1];
    const float* bq1 = (const float*)d_in[2];
    const float* Wp1 = (const float*)d_in[3];
    const float* bp1 = (const float*)d_in[4];
    const float* Wq2 = (const float*)d_in[5];
    const float* bq2 = (const float*)d_in[6];
    const float* Wp2 = (const float*)d_in[7];
    const float* bp2 = (const float*)d_in[8];
    const float* Wg  = (const float*)d_in[9];
    const float* bg  = (const float*)d_in[10];
    float* out = (float*)d_out;

    const size_t plane = (size_t)TOK * CC;             // dwords per packed plane
    unsigned* q1p = (unsigned*)d_ws;
    unsigned* q2p = q1p + plane;
    float*   sums = (float*)(q2p + plane);             // 256 floats (zeroed by qproj)

    qproj_kernel<<<dim3(TOK / QTOK), 512, 0, stream>>>(x, Wq1, Wq2, bq1, bq2,
                                                       q1p, q2p, sums);
    attn_kernel<<<dim3(248), 1024, 0, stream>>>(q1p, q2p, sums);
    oproj_kernel<<<dim3(496), 512, 0, stream>>>(q1p, q2p,
                                                Wp1, Wp2, bp1, bp2, Wg, bg,
                                                sums, out);
}